// Round 2
// 545.414 us; speedup vs baseline: 1.0713x; 1.0713x over previous
//
#include <hip/hip_runtime.h>

// FNO spectral block: x(32,256,4096), weight(256,256,128,2) -> out (dtype of x).
// Runtime dtype probe (fp32 vs bf16); bf16-MFMA internally, fp32 accumulation.
// probe -> basis -> fwd gemm (trunc rDFT, full K, fused transpose/pack to
// Xp[ic][b][m]) -> mix (o-pair blocks, coalesced weight stream) ->
// inv gemm (irDFT + LeakyReLU + residual, LDS-staged vectorized epilogue).

typedef unsigned short u16;
typedef unsigned int   u32;
typedef __attribute__((ext_vector_type(8))) short bf16x8;
typedef __attribute__((ext_vector_type(4))) float f32x4;

#define MLEN  4096

__device__ __forceinline__ u16 f2b(float f) {           // fp32 -> bf16 RNE
  u32 u = __float_as_uint(f);
  u += 0x7fffu + ((u >> 16) & 1u);
  return (u16)(u >> 16);
}
__device__ __forceinline__ float blo(u32 p) { return __uint_as_float(p << 16); }
__device__ __forceinline__ float bhi(u32 p) { return __uint_as_float(p & 0xffff0000u); }

// ------------------------------------------------------------- dtype probe
__global__ void probe_kernel(const u16* __restrict__ x16, int* __restrict__ flag) {
  __shared__ int cnt;
  if (threadIdx.x == 0) cnt = 0;
  __syncthreads();
  int c = 0;
  for (int j = threadIdx.x; j < 4096; j += 256) {
    u32 e = (x16[j] >> 7) & 0xFFu;
    if (e >= 0x8Fu) ++c;
  }
  atomicAdd(&cnt, c);
  __syncthreads();
  if (threadIdx.x == 0) flag[0] = (cnt > 256) ? 0 : 1;   // 0=fp32, 1=bf16
}

// ---------------------------------------------------------------- basis
__global__ void basis_kernel(u16* __restrict__ Bas1, u16* __restrict__ Bas2) {
  int t = blockIdx.x;           // 0..4095
  int c = threadIdx.x;          // 0..255
  int m = c & 127;
  int idx = (m * t) & 4095;
  float theta = (float)idx * (6.283185307179586f / 4096.0f);
  float s, cth;
  __sincosf(theta, &s, &cth);
  float v = (c < 128) ? cth : -s;
  u16 bv = f2b(v);
  Bas2[t * 256 + c] = bv;
  Bas1[c * 4096 + t] = bv;
}

// ---------------------------------------------------------------- GEMM (NT)
// C = A(MxK,row,lda) * Bt(NxK,row,ldb)^T.
// EPI=1: out[row*ldc+col] = x + leakyrelu(C); LDS-staged, float4/uint4 IO.
// EPI=2: pack C to bf16 Xp[ic][b][m] = u32(Re(m)=col m, Im(m)=col 128+m);
//        row = b*256+ic. LDS-staged, 256B-contiguous u32 stores.
template <int BM, int BN, int EPI, bool ADUAL>
__global__ __launch_bounds__(256)
void gemm_nt(const void* __restrict__ A, const u16* __restrict__ Bt,
             int K, int lda, int ldb,
             u32* __restrict__ Xp, int ldc,
             const void* __restrict__ xres, void* __restrict__ outp,
             const int* __restrict__ flag) {
  constexpr int LD = 72;                 // 64+8 pad: <=2-way LDS conflicts (free)
  constexpr int FM = BM / 32;
  constexpr int FN = BN / 32;
  __shared__ __align__(16) char smem[(BM + BN) * LD * 2];
  u16* As = (u16*)smem;
  u16* Bs = (u16*)(smem + BM * LD * 2);
  const int mode = (ADUAL || EPI == 1) ? flag[0] : 1;
  const int tid = threadIdx.x;
  const int bn0 = blockIdx.x * BN;
  const int bm0 = blockIdx.y * BM;
  const int lane = tid & 63;
  const int wave = tid >> 6;
  const int wm = wave >> 1, wn = wave & 1;
  const int l15 = lane & 15, q4 = lane >> 4;

  f32x4 acc[FM][FN] = {};

  for (int kt = 0; kt < K; kt += 64) {
    __syncthreads();
    if (!ADUAL || mode == 1) {
      const u16* Ab = (const u16*)A;
#pragma unroll
      for (int q = tid; q < BM * 8; q += 256) {
        int row = q >> 3, c8 = q & 7;
        *(uint4*)&As[row * LD + c8 * 8] =
            *(const uint4*)&Ab[(size_t)(bm0 + row) * lda + kt + c8 * 8];
      }
    } else {
      const float* Af = (const float*)A;
#pragma unroll
      for (int q = tid; q < BM * 8; q += 256) {
        int row = q >> 3, c8 = q & 7;
        const float* src = &Af[(size_t)(bm0 + row) * lda + kt + c8 * 8];
        float4 f0 = *(const float4*)src;
        float4 f1 = *(const float4*)(src + 4);
        u16 tmp[8] = {f2b(f0.x), f2b(f0.y), f2b(f0.z), f2b(f0.w),
                      f2b(f1.x), f2b(f1.y), f2b(f1.z), f2b(f1.w)};
        *(uint4*)&As[row * LD + c8 * 8] = *(const uint4*)tmp;
      }
    }
#pragma unroll
    for (int q = tid; q < BN * 8; q += 256) {
      int row = q >> 3, c8 = q & 7;
      *(uint4*)&Bs[row * LD + c8 * 8] =
          *(const uint4*)&Bt[(size_t)(bn0 + row) * ldb + kt + c8 * 8];
    }
    __syncthreads();
#pragma unroll
    for (int kk = 0; kk < 2; ++kk) {
      const int ko = kk * 32 + q4 * 8;
      bf16x8 af[FM], bfr[FN];
#pragma unroll
      for (int mi = 0; mi < FM; ++mi)
        af[mi] = *(const bf16x8*)&As[(wm * (BM / 2) + mi * 16 + l15) * LD + ko];
#pragma unroll
      for (int ni = 0; ni < FN; ++ni)
        bfr[ni] = *(const bf16x8*)&Bs[(wn * (BN / 2) + ni * 16 + l15) * LD + ko];
#pragma unroll
      for (int mi = 0; mi < FM; ++mi)
#pragma unroll
        for (int ni = 0; ni < FN; ++ni)
          acc[mi][ni] = __builtin_amdgcn_mfma_f32_16x16x32_bf16(
              af[mi], bfr[ni], acc[mi][ni], 0, 0, 0);
    }
  }

  // --------------- epilogues (smem reused; As/Bs dead after barrier) -------
  if constexpr (EPI == 1) {
    // acc rows: wm*(BM/2)+mi*16+q4*4+r ; cols: wn*64+ni*16+l15 (BN=128)
    float* Cs = (float*)smem;            // [32][132] fp32 chunk, per mi
    const int s = tid >> 3;              // 0..31 staged row
    const int c8 = tid & 7;
#pragma unroll
    for (int mi = 0; mi < FM; ++mi) {
      __syncthreads();
#pragma unroll
      for (int ni = 0; ni < FN; ++ni) {
        float* dst = &Cs[(wm * 16 + q4 * 4) * 132 + wn * 64 + ni * 16 + l15];
#pragma unroll
        for (int r = 0; r < 4; ++r) dst[r * 132] = acc[mi][ni][r];
      }
      __syncthreads();
      const int gr = bm0 + mi * 16 + s + ((s < 16) ? 0 : (BM / 2 - 16));
      if (mode == 1) {
        const u16* xr16 = (const u16*)xres;
        u16* o16 = (u16*)outp;
#pragma unroll
        for (int i = 0; i < 2; ++i) {
          const int cb = c8 * 8 + i * 64;
          float4 va = *(const float4*)&Cs[s * 132 + cb];
          float4 vb = *(const float4*)&Cs[s * 132 + cb + 4];
          size_t gidx = (size_t)gr * ldc + bn0 + cb;
          uint4 xv = *(const uint4*)&xr16[gidx];
          float cv[8] = {va.x, va.y, va.z, va.w, vb.x, vb.y, vb.z, vb.w};
          u32 xw[4] = {xv.x, xv.y, xv.z, xv.w};
          u16 ov[8];
#pragma unroll
          for (int j = 0; j < 4; ++j) {
            float l0 = cv[2 * j]     >= 0.f ? cv[2 * j]     : 0.2f * cv[2 * j];
            float l1 = cv[2 * j + 1] >= 0.f ? cv[2 * j + 1] : 0.2f * cv[2 * j + 1];
            ov[2 * j]     = f2b(blo(xw[j]) + l0);
            ov[2 * j + 1] = f2b(bhi(xw[j]) + l1);
          }
          *(uint4*)&o16[gidx] = *(const uint4*)ov;
        }
      } else {
        const float* xf = (const float*)xres;
        float* of = (float*)outp;
#pragma unroll
        for (int i = 0; i < 4; ++i) {
          const int cb = c8 * 4 + i * 32;
          float4 v = *(const float4*)&Cs[s * 132 + cb];
          size_t gidx = (size_t)gr * ldc + bn0 + cb;
          float4 xv = *(const float4*)&xf[gidx];
          float4 o;
          o.x = xv.x + (v.x >= 0.f ? v.x : 0.2f * v.x);
          o.y = xv.y + (v.y >= 0.f ? v.y : 0.2f * v.y);
          o.z = xv.z + (v.z >= 0.f ? v.z : 0.2f * v.z);
          o.w = xv.w + (v.w >= 0.f ? v.w : 0.2f * v.w);
          *(float4*)&of[gidx] = o;
        }
      }
    }
  } else {
    // EPI==2: BM=32 (FM=1), BN=256. rows 0..31 = ic, block row-band = (b, ic0).
    u16* Ls = (u16*)smem;                // [32][264] bf16 tile
    __syncthreads();
#pragma unroll
    for (int ni = 0; ni < FN; ++ni) {
      u16* dst = &Ls[(wm * 16 + q4 * 4) * 264 + wn * 128 + ni * 16 + l15];
#pragma unroll
      for (int r = 0; r < 4; ++r) dst[r * 264] = f2b(acc[0][ni][r]);
    }
    __syncthreads();
    const int b   = bm0 >> 8;
    const int ic0 = bm0 & 255;
    const int m   = tid & 127, ich = tid >> 7;
#pragma unroll
    for (int i2 = 0; i2 < 16; ++i2) {
      int ic = i2 * 2 + ich;
      u32 v = (u32)Ls[ic * 264 + m] | ((u32)Ls[ic * 264 + 128 + m] << 16);
      Xp[((size_t)(ic0 + ic) * 32 + b) * 128 + m] = v;
    }
  }
}

// ---------------------------------------------------------------- mode mix
// Y[b,o,m] = sum_i X[b,i,m]*w[o,i,m] (complex). Block = (o-pair, b-half),
// 1024 thr: wave>>3 -> o_local, wave&7 -> b-pair, lane -> m-pair.
// Weight streamed fully contiguous; X from Xp[ic][b][m] coalesced.
// Writes Yp bf16 pre-scaled for inverse GEMM.
__global__ __launch_bounds__(1024)
void mix_kernel(const u32* __restrict__ Xp, const void* __restrict__ w,
                u16* __restrict__ Yp, const int* __restrict__ flag) {
  const int tid = threadIdx.x;
  const int wave = tid >> 6, lane = tid & 63;
  const int o = blockIdx.x * 2 + (wave >> 3);
  const int b0 = blockIdx.y * 16 + (wave & 7) * 2;
  const int m = lane * 2;
  const int mode = flag[0];

  float ar[2][2] = {}, ai[2][2] = {};    // [b][mi]

  if (mode == 0) {
    const float* wb = (const float*)w + 2u * ((size_t)o * 32768 + m);
#pragma unroll 4
    for (int ic = 0; ic < 256; ++ic) {
      float4 wp = *(const float4*)&wb[(size_t)ic * 256];
      uint2 xa = *(const uint2*)&Xp[((size_t)ic * 32 + b0) * 128 + m];
      uint2 xb = *(const uint2*)&Xp[((size_t)ic * 32 + b0 + 1) * 128 + m];
      float wr0 = wp.x, wi0 = wp.y, wr1 = wp.z, wi1 = wp.w;
      float xr, xi;
      xr = blo(xa.x); xi = bhi(xa.x);
      ar[0][0] = fmaf(xr, wr0, fmaf(-xi, wi0, ar[0][0]));
      ai[0][0] = fmaf(xr, wi0, fmaf(xi, wr0, ai[0][0]));
      xr = blo(xa.y); xi = bhi(xa.y);
      ar[0][1] = fmaf(xr, wr1, fmaf(-xi, wi1, ar[0][1]));
      ai[0][1] = fmaf(xr, wi1, fmaf(xi, wr1, ai[0][1]));
      xr = blo(xb.x); xi = bhi(xb.x);
      ar[1][0] = fmaf(xr, wr0, fmaf(-xi, wi0, ar[1][0]));
      ai[1][0] = fmaf(xr, wi0, fmaf(xi, wr0, ai[1][0]));
      xr = blo(xb.y); xi = bhi(xb.y);
      ar[1][1] = fmaf(xr, wr1, fmaf(-xi, wi1, ar[1][1]));
      ai[1][1] = fmaf(xr, wi1, fmaf(xi, wr1, ai[1][1]));
    }
  } else {
    const u32* wb = (const u32*)w + (size_t)o * 32768 + m;
#pragma unroll 4
    for (int ic = 0; ic < 256; ++ic) {
      uint2 wp = *(const uint2*)&wb[(size_t)ic * 128];
      uint2 xa = *(const uint2*)&Xp[((size_t)ic * 32 + b0) * 128 + m];
      uint2 xb = *(const uint2*)&Xp[((size_t)ic * 32 + b0 + 1) * 128 + m];
      float wr0 = blo(wp.x), wi0 = bhi(wp.x), wr1 = blo(wp.y), wi1 = bhi(wp.y);
      float xr, xi;
      xr = blo(xa.x); xi = bhi(xa.x);
      ar[0][0] = fmaf(xr, wr0, fmaf(-xi, wi0, ar[0][0]));
      ai[0][0] = fmaf(xr, wi0, fmaf(xi, wr0, ai[0][0]));
      xr = blo(xa.y); xi = bhi(xa.y);
      ar[0][1] = fmaf(xr, wr1, fmaf(-xi, wi1, ar[0][1]));
      ai[0][1] = fmaf(xr, wi1, fmaf(xi, wr1, ai[0][1]));
      xr = blo(xb.x); xi = bhi(xb.x);
      ar[1][0] = fmaf(xr, wr0, fmaf(-xi, wi0, ar[1][0]));
      ai[1][0] = fmaf(xr, wi0, fmaf(xi, wr0, ai[1][0]));
      xr = blo(xb.y); xi = bhi(xb.y);
      ar[1][1] = fmaf(xr, wr1, fmaf(-xi, wi1, ar[1][1]));
      ai[1][1] = fmaf(xr, wi1, fmaf(xi, wr1, ai[1][1]));
    }
  }

  const float sIm = 2.0f / 4096.0f;
  const float sRe0 = (m == 0) ? (1.0f / 4096.0f) : (2.0f / 4096.0f);
  const float sRe1 = 2.0f / 4096.0f;
  u32* Yp32 = (u32*)Yp;
#pragma unroll
  for (int jb = 0; jb < 2; ++jb) {
    int b = b0 + jb;
    size_t base = ((size_t)(b * 256 + o)) * 128;   // u32 index
    u32 re = (u32)f2b(ar[jb][0] * sRe0) | ((u32)f2b(ar[jb][1] * sRe1) << 16);
    u32 im = (u32)f2b(ai[jb][0] * sIm) | ((u32)f2b(ai[jb][1] * sIm) << 16);
    Yp32[base + lane] = re;
    Yp32[base + 64 + lane] = im;
  }
}

// ---------------------------------------------------------------- launch
extern "C" void kernel_launch(void* const* d_in, const int* in_sizes, int n_in,
                              void* d_out, int out_size, void* d_ws, size_t ws_size,
                              hipStream_t stream) {
  const void* x = d_in[0];                // (32,256,4096) fp32 or bf16
  const void* w = d_in[1];                // (256,256,128,2) fp32 or bf16

  char* ws = (char*)d_ws;
  int*  flag = (int*)(ws);
  u16*  Bas1 = (u16*)(ws + (1u << 20));   // 2 MB  [c=256][t=4096]
  u16*  Bas2 = (u16*)(ws + (3u << 20));   // 2 MB  [t=4096][c=256]
  u32*  Xp   = (u32*)(ws + (5u << 20));   // 4 MB  [ic][b][m] packed(re,im)
  u16*  Yp   = (u16*)(ws + (9u << 20));   // 4 MB

  probe_kernel<<<dim3(1), dim3(256), 0, stream>>>((const u16*)x, flag);
  basis_kernel<<<dim3(4096), dim3(256), 0, stream>>>(Bas1, Bas2);

  // forward truncated rDFT, full K, fused transpose/pack into Xp[ic][b][m]
  gemm_nt<32, 256, 2, true><<<dim3(1, 256, 1), dim3(256), 0, stream>>>(
      x, Bas1, MLEN, MLEN, MLEN, Xp, 0, nullptr, nullptr, flag);

  // per-mode complex channel mix -> Yp (bf16, irfft scaling folded in)
  mix_kernel<<<dim3(128, 2), dim3(1024), 0, stream>>>(Xp, w, Yp, flag);

  // inverse DFT + LeakyReLU + residual (vectorized LDS-staged epilogue)
  gemm_nt<128, 128, 1, false><<<dim3(32, 64, 1), dim3(256), 0, stream>>>(
      Yp, Bas2, 256, 256, 256, nullptr, MLEN, x, d_out, flag);
}

// Round 14
// 464.903 us; speedup vs baseline: 1.2568x; 1.1732x over previous
//
#include <hip/hip_runtime.h>

// FNO spectral block: x(32,256,4096), weight(256,256,128,2) -> out (dtype of x).
// Runtime dtype probe (fp32 vs bf16); bf16-MFMA internally, fp32 accumulation.
// probe -> basis -> fwd gemm (radix-2 folded rDFT: K=2048, parity grid.z,
// fused pack to parity-split Xpp[p][ic][b][m/2]) -> mix (writes parity-grouped
// (re,im) pairs) -> inv gemm (radix-2 folded irDFT: K=128 per parity, butterfly
// epilogue writes t' and t'+2048, + LeakyReLU + residual).

typedef unsigned short u16;
typedef unsigned int   u32;
typedef __attribute__((ext_vector_type(8))) short bf16x8;
typedef __attribute__((ext_vector_type(4))) float f32x4;

#define MLEN  4096

__device__ __forceinline__ u16 f2b(float f) {           // fp32 -> bf16 RNE
  u32 u = __float_as_uint(f);
  u += 0x7fffu + ((u >> 16) & 1u);
  return (u16)(u >> 16);
}
__device__ __forceinline__ float blo(u32 p) { return __uint_as_float(p << 16); }
__device__ __forceinline__ float bhi(u32 p) { return __uint_as_float(p & 0xffff0000u); }

// ------------------------------------------------------------- dtype probe
__global__ void probe_kernel(const u16* __restrict__ x16, int* __restrict__ flag) {
  __shared__ int cnt;
  if (threadIdx.x == 0) cnt = 0;
  __syncthreads();
  int c = 0;
  for (int j = threadIdx.x; j < 4096; j += 256) {
    u32 e = (x16[j] >> 7) & 0xFFu;
    if (e >= 0x8Fu) ++c;
  }
  atomicAdd(&cnt, c);
  __syncthreads();
  if (threadIdx.x == 0) flag[0] = (cnt > 256) ? 0 : 1;   // 0=fp32, 1=bf16
}

// ---------------------------------------------------------------- basis
// Bas1P [r=256][t'=2048]: r = parity*128 + isim*64 + j, mode m = 2j+parity;
//       isim=0 -> cos, isim=1 -> -sin.  (radix-2 folded forward basis)
// Bas2P [t'=2048][c=256]: c = p*128 + 2j + s, mode m = 2j+p;
//       s=0 -> cos(2pi m t'/4096), s=1 -> -sin.  (parity-grouped inverse basis)
__global__ void basis_kernel(u16* __restrict__ Bas1P, u16* __restrict__ Bas2P) {
  int t = blockIdx.x;           // 0..2047
  int c = threadIdx.x;          // 0..255
  {
    int p = c >> 7, rem = c & 127, j = rem >> 1, s2 = rem & 1;
    int m = 2 * j + p;
    int idx = (m * t) & 4095;
    float theta = (float)idx * (6.283185307179586f / 4096.0f);
    float s, cth;
    __sincosf(theta, &s, &cth);
    Bas2P[t * 256 + c] = f2b(s2 ? -s : cth);
  }
  {
    int parity = c >> 7, isim = (c >> 6) & 1, j = c & 63;
    int m = 2 * j + parity;
    int idx = (m * t) & 4095;
    float theta = (float)idx * (6.283185307179586f / 4096.0f);
    float s, cth;
    __sincosf(theta, &s, &cth);
    Bas1P[c * 2048 + t] = f2b(isim ? -s : cth);
  }
}

// ---------------------------------------------------------------- GEMM (NT)
// C = A(MxK,row,lda) * Bt(NxK,row,ldb)^T.
// EPI=1: radix-2 inverse. K=256: kt<128 -> accE (even modes), kt>=128 -> accO.
//        Epilogue: out[gr][bn0+t'] = x + lrelu(E+O); out[gr][bn0+2048+t'] =
//        x + lrelu(E-O). LDS-staged, float4/uint4 IO.
// EPI=2: radix-2 forward: p=blockIdx.z parity; A-load folds
//        a = x[t] +/- x[t+2048] (fp32, then one bf16 round); Bt offset by
//        p*BN rows; pack C to Xpp[p][ic][b][j] = u32(Re_j, Im_j), j=m>>1.
template <int BM, int BN, int EPI, bool ADUAL>
__global__ __launch_bounds__(256)
void gemm_nt(const void* __restrict__ A, const u16* __restrict__ Bt,
             int K, int lda, int ldb,
             u32* __restrict__ Xp, int ldc,
             const void* __restrict__ xres, void* __restrict__ outp,
             const int* __restrict__ flag) {
  constexpr int LD = 72;                 // 64+8 pad: <=2-way LDS conflicts (free)
  constexpr int FM = BM / 32;
  constexpr int FN = BN / 32;
  __shared__ __align__(16) char smem[(BM + BN) * LD * 2];
  u16* As = (u16*)smem;
  u16* Bs = (u16*)(smem + BM * LD * 2);
  const int mode = (ADUAL || EPI == 1) ? flag[0] : 1;
  const int tid = threadIdx.x;
  const int bn0 = blockIdx.x * BN;
  const int bm0 = blockIdx.y * BM;
  const int lane = tid & 63;
  const int wave = tid >> 6;
  const int wm = wave >> 1, wn = wave & 1;
  const int l15 = lane & 15, q4 = lane >> 4;

  const u16* Btb = Bt;
  if constexpr (EPI == 2) Btb += (size_t)blockIdx.z * BN * ldb;

  f32x4 acc[FM][FN] = {};    // EPI==1: even-mode accumulator E
  f32x4 acc2[FM][FN] = {};   // EPI==1: odd-mode accumulator O (else unused/DCE)

  // one 64-wide K-step of MFMAs into the given accumulator (static indexing)
  auto kstep = [&](f32x4 (&ac)[FM][FN]) {
#pragma unroll
    for (int kk = 0; kk < 2; ++kk) {
      const int ko = kk * 32 + q4 * 8;
      bf16x8 af[FM], bfr[FN];
#pragma unroll
      for (int mi = 0; mi < FM; ++mi)
        af[mi] = *(const bf16x8*)&As[(wm * (BM / 2) + mi * 16 + l15) * LD + ko];
#pragma unroll
      for (int ni = 0; ni < FN; ++ni)
        bfr[ni] = *(const bf16x8*)&Bs[(wn * (BN / 2) + ni * 16 + l15) * LD + ko];
#pragma unroll
      for (int mi = 0; mi < FM; ++mi)
#pragma unroll
        for (int ni = 0; ni < FN; ++ni)
          ac[mi][ni] = __builtin_amdgcn_mfma_f32_16x16x32_bf16(
              af[mi], bfr[ni], ac[mi][ni], 0, 0, 0);
    }
  };

  for (int kt = 0; kt < K; kt += 64) {
    __syncthreads();
    if constexpr (EPI == 2) {
      // radix-2 fold: a = x[row][kt+c] +/- x[row][kt+2048+c]
      const int neg = blockIdx.z;
#pragma unroll
      for (int q = tid; q < BM * 8; q += 256) {
        int row = q >> 3, c8 = q & 7;
        u16 tmp[8];
        if (mode == 1) {
          const u16* s0 = &((const u16*)A)[(size_t)(bm0 + row) * lda + kt + c8 * 8];
          uint4 a0 = *(const uint4*)s0;
          uint4 a1 = *(const uint4*)(s0 + 2048);
          u32 aw[4] = {a0.x, a0.y, a0.z, a0.w};
          u32 bw[4] = {a1.x, a1.y, a1.z, a1.w};
#pragma unroll
          for (int j = 0; j < 4; ++j) {
            float lo = neg ? (blo(aw[j]) - blo(bw[j])) : (blo(aw[j]) + blo(bw[j]));
            float hi = neg ? (bhi(aw[j]) - bhi(bw[j])) : (bhi(aw[j]) + bhi(bw[j]));
            tmp[2 * j]     = f2b(lo);
            tmp[2 * j + 1] = f2b(hi);
          }
        } else {
          const float* s0 = &((const float*)A)[(size_t)(bm0 + row) * lda + kt + c8 * 8];
          float4 f0 = *(const float4*)s0;
          float4 f1 = *(const float4*)(s0 + 4);
          float4 g0 = *(const float4*)(s0 + 2048);
          float4 g1 = *(const float4*)(s0 + 2052);
          float a[8] = {f0.x, f0.y, f0.z, f0.w, f1.x, f1.y, f1.z, f1.w};
          float b[8] = {g0.x, g0.y, g0.z, g0.w, g1.x, g1.y, g1.z, g1.w};
#pragma unroll
          for (int j = 0; j < 8; ++j)
            tmp[j] = f2b(neg ? (a[j] - b[j]) : (a[j] + b[j]));
        }
        *(uint4*)&As[row * LD + c8 * 8] = *(const uint4*)tmp;
      }
    } else {
      const u16* Ab = (const u16*)A;
#pragma unroll
      for (int q = tid; q < BM * 8; q += 256) {
        int row = q >> 3, c8 = q & 7;
        *(uint4*)&As[row * LD + c8 * 8] =
            *(const uint4*)&Ab[(size_t)(bm0 + row) * lda + kt + c8 * 8];
      }
    }
#pragma unroll
    for (int q = tid; q < BN * 8; q += 256) {
      int row = q >> 3, c8 = q & 7;
      *(uint4*)&Bs[row * LD + c8 * 8] =
          *(const uint4*)&Btb[(size_t)(bn0 + row) * ldb + kt + c8 * 8];
    }
    __syncthreads();
    if constexpr (EPI == 1) {
      if (kt >= 128) kstep(acc2); else kstep(acc);
    } else {
      kstep(acc);
    }
  }

  // --------------- epilogues (smem reused; As/Bs dead after barrier) -------
  if constexpr (EPI == 1) {
    // acc rows: wm*64+mi*16+q4*4+r ; cols: wn*32+ni*16+l15 (BN=64).
    // Butterfly: col t'=bn0+cc gets E+O, col bn0+2048+cc gets E-O.
    float* Cs = (float*)smem;            // [32][136]: 0..67 sum, 68..135 diff
    const int s = tid >> 3;              // 0..31 staged row
    const int c8 = tid & 7;
#pragma unroll
    for (int mi = 0; mi < FM; ++mi) {
      __syncthreads();
#pragma unroll
      for (int ni = 0; ni < FN; ++ni) {
        float* dst = &Cs[(wm * 16 + q4 * 4) * 136 + wn * 32 + ni * 16 + l15];
#pragma unroll
        for (int r = 0; r < 4; ++r) {
          float e = acc[mi][ni][r], o = acc2[mi][ni][r];
          dst[r * 136]      = e + o;
          dst[r * 136 + 68] = e - o;
        }
      }
      __syncthreads();
      const int gr = bm0 + mi * 16 + s + ((s < 16) ? 0 : (BM / 2 - 16));
      if (mode == 1) {
        const u16* xr16 = (const u16*)xres;
        u16* o16 = (u16*)outp;
#pragma unroll
        for (int h = 0; h < 2; ++h) {
          float4 va = *(const float4*)&Cs[s * 136 + h * 68 + c8 * 8];
          float4 vb = *(const float4*)&Cs[s * 136 + h * 68 + c8 * 8 + 4];
          size_t gidx = (size_t)gr * ldc + bn0 + h * 2048 + c8 * 8;
          uint4 xv = *(const uint4*)&xr16[gidx];
          float cv[8] = {va.x, va.y, va.z, va.w, vb.x, vb.y, vb.z, vb.w};
          u32 xw[4] = {xv.x, xv.y, xv.z, xv.w};
          u16 ov[8];
#pragma unroll
          for (int j = 0; j < 4; ++j) {
            float l0 = cv[2 * j]     >= 0.f ? cv[2 * j]     : 0.2f * cv[2 * j];
            float l1 = cv[2 * j + 1] >= 0.f ? cv[2 * j + 1] : 0.2f * cv[2 * j + 1];
            ov[2 * j]     = f2b(blo(xw[j]) + l0);
            ov[2 * j + 1] = f2b(bhi(xw[j]) + l1);
          }
          *(uint4*)&o16[gidx] = *(const uint4*)ov;
        }
      } else {
        const float* xf = (const float*)xres;
        float* of = (float*)outp;
#pragma unroll
        for (int h = 0; h < 2; ++h) {
          float4 v0 = *(const float4*)&Cs[s * 136 + h * 68 + c8 * 8];
          float4 v1 = *(const float4*)&Cs[s * 136 + h * 68 + c8 * 8 + 4];
          size_t gidx = (size_t)gr * ldc + bn0 + h * 2048 + c8 * 8;
          float4 x0 = *(const float4*)&xf[gidx];
          float4 x1 = *(const float4*)&xf[gidx + 4];
          float4 o0, o1;
          o0.x = x0.x + (v0.x >= 0.f ? v0.x : 0.2f * v0.x);
          o0.y = x0.y + (v0.y >= 0.f ? v0.y : 0.2f * v0.y);
          o0.z = x0.z + (v0.z >= 0.f ? v0.z : 0.2f * v0.z);
          o0.w = x0.w + (v0.w >= 0.f ? v0.w : 0.2f * v0.w);
          o1.x = x1.x + (v1.x >= 0.f ? v1.x : 0.2f * v1.x);
          o1.y = x1.y + (v1.y >= 0.f ? v1.y : 0.2f * v1.y);
          o1.z = x1.z + (v1.z >= 0.f ? v1.z : 0.2f * v1.z);
          o1.w = x1.w + (v1.w >= 0.f ? v1.w : 0.2f * v1.w);
          *(float4*)&of[gidx] = o0;
          *(float4*)&of[gidx + 4] = o1;
        }
      }
    }
  } else {
    // EPI==2: BM=32 (FM=1), BN=128. cols c<64 -> Re(mode 2c+p), c>=64 -> Im.
    constexpr int LP = 136;              // 128+8 pad
    u16* Ls = (u16*)smem;                // [32][136] bf16 tile
    __syncthreads();
#pragma unroll
    for (int ni = 0; ni < FN; ++ni) {
      u16* dst = &Ls[(wm * 16 + q4 * 4) * LP + wn * 64 + ni * 16 + l15];
#pragma unroll
      for (int r = 0; r < 4; ++r) dst[r * LP] = f2b(acc[0][ni][r]);
    }
    __syncthreads();
    const int b   = bm0 >> 8;
    const int ic0 = bm0 & 255;
    const int j   = tid & 63, ich = tid >> 6;
    u32* dstX = Xp + (size_t)blockIdx.z * (256 * 32 * 64);
#pragma unroll
    for (int i2 = 0; i2 < 8; ++i2) {
      int ic = i2 * 4 + ich;
      u32 v = (u32)Ls[ic * LP + j] | ((u32)Ls[ic * LP + 64 + j] << 16);
      dstX[((size_t)(ic0 + ic) * 32 + b) * 64 + j] = v;
    }
  }
}

// ---------------------------------------------------------------- mode mix
// Y[b,o,m] = sum_i X[b,i,m]*w[o,i,m] (complex). Block = (o-pair, b-half),
// 1024 thr: wave>>3 -> o_local, wave&7 -> b-pair, lane -> mode pair
// (even mode 2*lane from Xpp[0], odd mode 2*lane+1 from Xpp[1]).
// Writes YpP for the folded inverse: u16 col layout per row (256 cols):
//   c = p*128 + 2j + s : s=0 -> Re(mode 2j+p), s=1 -> Im.  As u32 words:
//   word p*64+j = (re, im) of mode 2j+p.  irfft scaling folded in.
__global__ __launch_bounds__(1024)
void mix_kernel(const u32* __restrict__ Xp, const void* __restrict__ w,
                u16* __restrict__ Yp, const int* __restrict__ flag) {
  const int tid = threadIdx.x;
  const int wave = tid >> 6, lane = tid & 63;
  const int o = blockIdx.x * 2 + (wave >> 3);
  const int b0 = blockIdx.y * 16 + (wave & 7) * 2;
  const int m = lane * 2;
  const int mode = flag[0];

  float ar[2][2] = {}, ai[2][2] = {};    // [b][parity]

  if (mode == 0) {
    const float* wb = (const float*)w + 2u * ((size_t)o * 32768 + m);
#pragma unroll 4
    for (int ic = 0; ic < 256; ++ic) {
      float4 wp = *(const float4*)&wb[(size_t)ic * 256];
      u32 xea = Xp[((size_t)ic * 32 + b0) * 64 + lane];
      u32 xoa = Xp[((size_t)(256 + ic) * 32 + b0) * 64 + lane];
      u32 xeb = Xp[((size_t)ic * 32 + b0 + 1) * 64 + lane];
      u32 xob = Xp[((size_t)(256 + ic) * 32 + b0 + 1) * 64 + lane];
      float wr0 = wp.x, wi0 = wp.y, wr1 = wp.z, wi1 = wp.w;
      float xr, xi;
      xr = blo(xea); xi = bhi(xea);
      ar[0][0] = fmaf(xr, wr0, fmaf(-xi, wi0, ar[0][0]));
      ai[0][0] = fmaf(xr, wi0, fmaf(xi, wr0, ai[0][0]));
      xr = blo(xoa); xi = bhi(xoa);
      ar[0][1] = fmaf(xr, wr1, fmaf(-xi, wi1, ar[0][1]));
      ai[0][1] = fmaf(xr, wi1, fmaf(xi, wr1, ai[0][1]));
      xr = blo(xeb); xi = bhi(xeb);
      ar[1][0] = fmaf(xr, wr0, fmaf(-xi, wi0, ar[1][0]));
      ai[1][0] = fmaf(xr, wi0, fmaf(xi, wr0, ai[1][0]));
      xr = blo(xob); xi = bhi(xob);
      ar[1][1] = fmaf(xr, wr1, fmaf(-xi, wi1, ar[1][1]));
      ai[1][1] = fmaf(xr, wi1, fmaf(xi, wr1, ai[1][1]));
    }
  } else {
    const u32* wb = (const u32*)w + (size_t)o * 32768 + m;
#pragma unroll 4
    for (int ic = 0; ic < 256; ++ic) {
      uint2 wp = *(const uint2*)&wb[(size_t)ic * 128];
      u32 xea = Xp[((size_t)ic * 32 + b0) * 64 + lane];
      u32 xoa = Xp[((size_t)(256 + ic) * 32 + b0) * 64 + lane];
      u32 xeb = Xp[((size_t)ic * 32 + b0 + 1) * 64 + lane];
      u32 xob = Xp[((size_t)(256 + ic) * 32 + b0 + 1) * 64 + lane];
      float wr0 = blo(wp.x), wi0 = bhi(wp.x), wr1 = blo(wp.y), wi1 = bhi(wp.y);
      float xr, xi;
      xr = blo(xea); xi = bhi(xea);
      ar[0][0] = fmaf(xr, wr0, fmaf(-xi, wi0, ar[0][0]));
      ai[0][0] = fmaf(xr, wi0, fmaf(xi, wr0, ai[0][0]));
      xr = blo(xoa); xi = bhi(xoa);
      ar[0][1] = fmaf(xr, wr1, fmaf(-xi, wi1, ar[0][1]));
      ai[0][1] = fmaf(xr, wi1, fmaf(xi, wr1, ai[0][1]));
      xr = blo(xeb); xi = bhi(xeb);
      ar[1][0] = fmaf(xr, wr0, fmaf(-xi, wi0, ar[1][0]));
      ai[1][0] = fmaf(xr, wi0, fmaf(xi, wr0, ai[1][0]));
      xr = blo(xob); xi = bhi(xob);
      ar[1][1] = fmaf(xr, wr1, fmaf(-xi, wi1, ar[1][1]));
      ai[1][1] = fmaf(xr, wi1, fmaf(xi, wr1, ai[1][1]));
    }
  }

  const float sIm = 2.0f / 4096.0f;
  const float sRe0 = (m == 0) ? (1.0f / 4096.0f) : (2.0f / 4096.0f);
  const float sRe1 = 2.0f / 4096.0f;
  u32* Yp32 = (u32*)Yp;
#pragma unroll
  for (int jb = 0; jb < 2; ++jb) {
    int b = b0 + jb;
    size_t base = ((size_t)(b * 256 + o)) * 128;   // u32 index
    u32 we = (u32)f2b(ar[jb][0] * sRe0) | ((u32)f2b(ai[jb][0] * sIm) << 16);
    u32 wo = (u32)f2b(ar[jb][1] * sRe1) | ((u32)f2b(ai[jb][1] * sIm) << 16);
    Yp32[base + lane] = we;          // even-mode (re,im) pair, word lane
    Yp32[base + 64 + lane] = wo;     // odd-mode  (re,im) pair, word 64+lane
  }
}

// ---------------------------------------------------------------- launch
extern "C" void kernel_launch(void* const* d_in, const int* in_sizes, int n_in,
                              void* d_out, int out_size, void* d_ws, size_t ws_size,
                              hipStream_t stream) {
  const void* x = d_in[0];                // (32,256,4096) fp32 or bf16
  const void* w = d_in[1];                // (256,256,128,2) fp32 or bf16

  char* ws = (char*)d_ws;
  int*  flag  = (int*)(ws);
  u16*  Bas1P = (u16*)(ws + (1u << 20)); // 1 MB  [r=256][t'=2048] fwd parity
  u16*  Bas2P = (u16*)(ws + (2u << 20)); // 1 MB  [t'=2048][c=256] inv parity
  u32*  Xpp   = (u32*)(ws + (4u << 20)); // 4 MB  [p][ic][b][j] packed(re,im)
  u16*  Yp    = (u16*)(ws + (8u << 20)); // 4 MB  parity-grouped (re,im)

  probe_kernel<<<dim3(1), dim3(256), 0, stream>>>((const u16*)x, flag);
  basis_kernel<<<dim3(2048), dim3(256), 0, stream>>>(Bas1P, Bas2P);

  // radix-2 folded forward rDFT: z=parity, K=2048, fused pack into Xpp
  gemm_nt<32, 128, 2, true><<<dim3(1, 256, 2), dim3(256), 0, stream>>>(
      x, Bas1P, 2048, MLEN, 2048, Xpp, 0, nullptr, nullptr, flag);

  // per-mode complex channel mix -> Yp (bf16, irfft scaling folded in)
  mix_kernel<<<dim3(128, 2), dim3(1024), 0, stream>>>(Xpp, w, Yp, flag);

  // radix-2 folded inverse DFT + LeakyReLU + residual (butterfly epilogue)
  gemm_nt<128, 64, 1, false><<<dim3(32, 64, 1), dim3(256), 0, stream>>>(
      Yp, Bas2P, 256, 256, 256, nullptr, MLEN, x, d_out, flag);
}

// Round 15
// 457.355 us; speedup vs baseline: 1.2776x; 1.0165x over previous
//
#include <hip/hip_runtime.h>

// FNO spectral block: x(32,256,4096), weight(256,256,128,2) -> out (dtype of x).
// probe -> basis -> fwd gemm (radix-2 folded rDFT, fused pack to interleaved
// Xp4[ic][bp][j] = uint4(e_b0,o_b0,e_b1,o_b1)) -> mix (1 uint4 X load/iter,
// unroll 8) -> inv gemm (radix-2 folded irDFT, butterfly epilogue).

typedef unsigned short u16;
typedef unsigned int   u32;
typedef __attribute__((ext_vector_type(8))) short bf16x8;
typedef __attribute__((ext_vector_type(4))) float f32x4;

#define MLEN  4096

__device__ __forceinline__ u16 f2b(float f) {           // fp32 -> bf16 RNE
  u32 u = __float_as_uint(f);
  u += 0x7fffu + ((u >> 16) & 1u);
  return (u16)(u >> 16);
}
__device__ __forceinline__ float blo(u32 p) { return __uint_as_float(p << 16); }
__device__ __forceinline__ float bhi(u32 p) { return __uint_as_float(p & 0xffff0000u); }

// ------------------------------------------------------------- dtype probe
__global__ void probe_kernel(const u16* __restrict__ x16, int* __restrict__ flag) {
  __shared__ int cnt;
  if (threadIdx.x == 0) cnt = 0;
  __syncthreads();
  int c = 0;
  for (int j = threadIdx.x; j < 4096; j += 256) {
    u32 e = (x16[j] >> 7) & 0xFFu;
    if (e >= 0x8Fu) ++c;
  }
  atomicAdd(&cnt, c);
  __syncthreads();
  if (threadIdx.x == 0) flag[0] = (cnt > 256) ? 0 : 1;   // 0=fp32, 1=bf16
}

// ---------------------------------------------------------------- basis
// Bas1P [r=256][t'=2048]: r = parity*128 + isim*64 + j, mode m = 2j+parity;
//       isim=0 -> cos, isim=1 -> -sin.  (radix-2 folded forward basis)
// Bas2P [t'=2048][c=256]: c = p*128 + 2j + s, mode m = 2j+p;
//       s=0 -> cos(2pi m t'/4096), s=1 -> -sin.  (parity-grouped inverse basis)
__global__ void basis_kernel(u16* __restrict__ Bas1P, u16* __restrict__ Bas2P) {
  int t = blockIdx.x;           // 0..2047
  int c = threadIdx.x;          // 0..255
  {
    int p = c >> 7, rem = c & 127, j = rem >> 1, s2 = rem & 1;
    int m = 2 * j + p;
    int idx = (m * t) & 4095;
    float theta = (float)idx * (6.283185307179586f / 4096.0f);
    float s, cth;
    __sincosf(theta, &s, &cth);
    Bas2P[t * 256 + c] = f2b(s2 ? -s : cth);
  }
  {
    int parity = c >> 7, isim = (c >> 6) & 1, j = c & 63;
    int m = 2 * j + parity;
    int idx = (m * t) & 4095;
    float theta = (float)idx * (6.283185307179586f / 4096.0f);
    float s, cth;
    __sincosf(theta, &s, &cth);
    Bas1P[c * 2048 + t] = f2b(isim ? -s : cth);
  }
}

// ---------------------------------------------------------------- GEMM (NT)
// C = A(MxK,row,lda) * Bt(NxK,row,ldb)^T.
// EPI=1: radix-2 inverse. K=256: kt<128 -> accE (even modes), kt>=128 -> accO.
//        Epilogue: out[gr][bn0+t'] = x + lrelu(E+O); out[gr][bn0+2048+t'] =
//        x + lrelu(E-O). LDS-staged, float4/uint4 IO.
// EPI=2: radix-2 forward: p=blockIdx.z parity; A-load folds
//        a = x[t] +/- x[t+2048]; pack C into interleaved Xp4:
//        u32 word index = (((ic)*16 + b/2)*64 + j)*4 + (b&1)*2 + p.
template <int BM, int BN, int EPI, bool ADUAL>
__global__ __launch_bounds__(256)
void gemm_nt(const void* __restrict__ A, const u16* __restrict__ Bt,
             int K, int lda, int ldb,
             u32* __restrict__ Xp, int ldc,
             const void* __restrict__ xres, void* __restrict__ outp,
             const int* __restrict__ flag) {
  constexpr int LD = 72;                 // 64+8 pad: <=2-way LDS conflicts (free)
  constexpr int FM = BM / 32;
  constexpr int FN = BN / 32;
  __shared__ __align__(16) char smem[(BM + BN) * LD * 2];
  u16* As = (u16*)smem;
  u16* Bs = (u16*)(smem + BM * LD * 2);
  const int mode = (ADUAL || EPI == 1) ? flag[0] : 1;
  const int tid = threadIdx.x;
  const int bn0 = blockIdx.x * BN;
  const int bm0 = blockIdx.y * BM;
  const int lane = tid & 63;
  const int wave = tid >> 6;
  const int wm = wave >> 1, wn = wave & 1;
  const int l15 = lane & 15, q4 = lane >> 4;

  const u16* Btb = Bt;
  if constexpr (EPI == 2) Btb += (size_t)blockIdx.z * BN * ldb;

  f32x4 acc[FM][FN] = {};    // EPI==1: even-mode accumulator E
  f32x4 acc2[FM][FN] = {};   // EPI==1: odd-mode accumulator O (else unused/DCE)

  // one 64-wide K-step of MFMAs into the given accumulator (static indexing)
  auto kstep = [&](f32x4 (&ac)[FM][FN]) {
#pragma unroll
    for (int kk = 0; kk < 2; ++kk) {
      const int ko = kk * 32 + q4 * 8;
      bf16x8 af[FM], bfr[FN];
#pragma unroll
      for (int mi = 0; mi < FM; ++mi)
        af[mi] = *(const bf16x8*)&As[(wm * (BM / 2) + mi * 16 + l15) * LD + ko];
#pragma unroll
      for (int ni = 0; ni < FN; ++ni)
        bfr[ni] = *(const bf16x8*)&Bs[(wn * (BN / 2) + ni * 16 + l15) * LD + ko];
#pragma unroll
      for (int mi = 0; mi < FM; ++mi)
#pragma unroll
        for (int ni = 0; ni < FN; ++ni)
          ac[mi][ni] = __builtin_amdgcn_mfma_f32_16x16x32_bf16(
              af[mi], bfr[ni], ac[mi][ni], 0, 0, 0);
    }
  };

  for (int kt = 0; kt < K; kt += 64) {
    __syncthreads();
    if constexpr (EPI == 2) {
      // radix-2 fold: a = x[row][kt+c] +/- x[row][kt+2048+c]
      const int neg = blockIdx.z;
#pragma unroll
      for (int q = tid; q < BM * 8; q += 256) {
        int row = q >> 3, c8 = q & 7;
        u16 tmp[8];
        if (mode == 1) {
          const u16* s0 = &((const u16*)A)[(size_t)(bm0 + row) * lda + kt + c8 * 8];
          uint4 a0 = *(const uint4*)s0;
          uint4 a1 = *(const uint4*)(s0 + 2048);
          u32 aw[4] = {a0.x, a0.y, a0.z, a0.w};
          u32 bw[4] = {a1.x, a1.y, a1.z, a1.w};
#pragma unroll
          for (int j = 0; j < 4; ++j) {
            float lo = neg ? (blo(aw[j]) - blo(bw[j])) : (blo(aw[j]) + blo(bw[j]));
            float hi = neg ? (bhi(aw[j]) - bhi(bw[j])) : (bhi(aw[j]) + bhi(bw[j]));
            tmp[2 * j]     = f2b(lo);
            tmp[2 * j + 1] = f2b(hi);
          }
        } else {
          const float* s0 = &((const float*)A)[(size_t)(bm0 + row) * lda + kt + c8 * 8];
          float4 f0 = *(const float4*)s0;
          float4 f1 = *(const float4*)(s0 + 4);
          float4 g0 = *(const float4*)(s0 + 2048);
          float4 g1 = *(const float4*)(s0 + 2052);
          float a[8] = {f0.x, f0.y, f0.z, f0.w, f1.x, f1.y, f1.z, f1.w};
          float b[8] = {g0.x, g0.y, g0.z, g0.w, g1.x, g1.y, g1.z, g1.w};
#pragma unroll
          for (int j = 0; j < 8; ++j)
            tmp[j] = f2b(neg ? (a[j] - b[j]) : (a[j] + b[j]));
        }
        *(uint4*)&As[row * LD + c8 * 8] = *(const uint4*)tmp;
      }
    } else {
      const u16* Ab = (const u16*)A;
#pragma unroll
      for (int q = tid; q < BM * 8; q += 256) {
        int row = q >> 3, c8 = q & 7;
        *(uint4*)&As[row * LD + c8 * 8] =
            *(const uint4*)&Ab[(size_t)(bm0 + row) * lda + kt + c8 * 8];
      }
    }
#pragma unroll
    for (int q = tid; q < BN * 8; q += 256) {
      int row = q >> 3, c8 = q & 7;
      *(uint4*)&Bs[row * LD + c8 * 8] =
          *(const uint4*)&Btb[(size_t)(bn0 + row) * ldb + kt + c8 * 8];
    }
    __syncthreads();
    if constexpr (EPI == 1) {
      if (kt >= 128) kstep(acc2); else kstep(acc);
    } else {
      kstep(acc);
    }
  }

  // --------------- epilogues (smem reused; As/Bs dead after barrier) -------
  if constexpr (EPI == 1) {
    // acc rows: wm*64+mi*16+q4*4+r ; cols: wn*32+ni*16+l15 (BN=64).
    // Butterfly: col t'=bn0+cc gets E+O, col bn0+2048+cc gets E-O.
    float* Cs = (float*)smem;            // [32][136]: 0..67 sum, 68..135 diff
    const int s = tid >> 3;              // 0..31 staged row
    const int c8 = tid & 7;
#pragma unroll
    for (int mi = 0; mi < FM; ++mi) {
      __syncthreads();
#pragma unroll
      for (int ni = 0; ni < FN; ++ni) {
        float* dst = &Cs[(wm * 16 + q4 * 4) * 136 + wn * 32 + ni * 16 + l15];
#pragma unroll
        for (int r = 0; r < 4; ++r) {
          float e = acc[mi][ni][r], o = acc2[mi][ni][r];
          dst[r * 136]      = e + o;
          dst[r * 136 + 68] = e - o;
        }
      }
      __syncthreads();
      const int gr = bm0 + mi * 16 + s + ((s < 16) ? 0 : (BM / 2 - 16));
      if (mode == 1) {
        const u16* xr16 = (const u16*)xres;
        u16* o16 = (u16*)outp;
#pragma unroll
        for (int h = 0; h < 2; ++h) {
          float4 va = *(const float4*)&Cs[s * 136 + h * 68 + c8 * 8];
          float4 vb = *(const float4*)&Cs[s * 136 + h * 68 + c8 * 8 + 4];
          size_t gidx = (size_t)gr * ldc + bn0 + h * 2048 + c8 * 8;
          uint4 xv = *(const uint4*)&xr16[gidx];
          float cv[8] = {va.x, va.y, va.z, va.w, vb.x, vb.y, vb.z, vb.w};
          u32 xw[4] = {xv.x, xv.y, xv.z, xv.w};
          u16 ov[8];
#pragma unroll
          for (int j = 0; j < 4; ++j) {
            float l0 = cv[2 * j]     >= 0.f ? cv[2 * j]     : 0.2f * cv[2 * j];
            float l1 = cv[2 * j + 1] >= 0.f ? cv[2 * j + 1] : 0.2f * cv[2 * j + 1];
            ov[2 * j]     = f2b(blo(xw[j]) + l0);
            ov[2 * j + 1] = f2b(bhi(xw[j]) + l1);
          }
          *(uint4*)&o16[gidx] = *(const uint4*)ov;
        }
      } else {
        const float* xf = (const float*)xres;
        float* of = (float*)outp;
#pragma unroll
        for (int h = 0; h < 2; ++h) {
          float4 v0 = *(const float4*)&Cs[s * 136 + h * 68 + c8 * 8];
          float4 v1 = *(const float4*)&Cs[s * 136 + h * 68 + c8 * 8 + 4];
          size_t gidx = (size_t)gr * ldc + bn0 + h * 2048 + c8 * 8;
          float4 x0 = *(const float4*)&xf[gidx];
          float4 x1 = *(const float4*)&xf[gidx + 4];
          float4 o0, o1;
          o0.x = x0.x + (v0.x >= 0.f ? v0.x : 0.2f * v0.x);
          o0.y = x0.y + (v0.y >= 0.f ? v0.y : 0.2f * v0.y);
          o0.z = x0.z + (v0.z >= 0.f ? v0.z : 0.2f * v0.z);
          o0.w = x0.w + (v0.w >= 0.f ? v0.w : 0.2f * v0.w);
          o1.x = x1.x + (v1.x >= 0.f ? v1.x : 0.2f * v1.x);
          o1.y = x1.y + (v1.y >= 0.f ? v1.y : 0.2f * v1.y);
          o1.z = x1.z + (v1.z >= 0.f ? v1.z : 0.2f * v1.z);
          o1.w = x1.w + (v1.w >= 0.f ? v1.w : 0.2f * v1.w);
          *(float4*)&of[gidx] = o0;
          *(float4*)&of[gidx + 4] = o1;
        }
      }
    }
  } else {
    // EPI==2: BM=32 (FM=1), BN=128. cols c<64 -> Re(mode 2c+p), c>=64 -> Im.
    // Write into interleaved Xp4: word = ((ic*16 + b/2)*64 + j)*4 + (b&1)*2 + z
    constexpr int LP = 136;              // 128+8 pad
    u16* Ls = (u16*)smem;                // [32][136] bf16 tile
    __syncthreads();
#pragma unroll
    for (int ni = 0; ni < FN; ++ni) {
      u16* dst = &Ls[(wm * 16 + q4 * 4) * LP + wn * 64 + ni * 16 + l15];
#pragma unroll
      for (int r = 0; r < 4; ++r) dst[r * LP] = f2b(acc[0][ni][r]);
    }
    __syncthreads();
    const int b   = bm0 >> 8;
    const int ic0 = bm0 & 255;
    const int j   = tid & 63, ich = tid >> 6;
    const int woff = (b & 1) * 2 + blockIdx.z;
    const int bp   = b >> 1;
#pragma unroll
    for (int i2 = 0; i2 < 8; ++i2) {
      int ic = i2 * 4 + ich;
      u32 v = (u32)Ls[ic * LP + j] | ((u32)Ls[ic * LP + 64 + j] << 16);
      Xp[((((size_t)(ic0 + ic) * 16 + bp) * 64 + j) << 2) + woff] = v;
    }
  }
}

// ---------------------------------------------------------------- mode mix
// Y[b,o,m] = sum_i X[b,i,m]*w[o,i,m] (complex). Block = (o-pair, b-half),
// 1024 thr: wave>>3 -> o_local, wave&7 -> b-pair, lane -> mode pair.
// X: ONE uint4 load per (ic, b-pair): (e_b0, o_b0, e_b1, o_b1).
// Weight streamed fully contiguous. Writes Yp parity-grouped (re,im) pairs
// pre-scaled for the folded inverse GEMM (layout unchanged from round 14).
__global__ __launch_bounds__(1024)
void mix_kernel(const u32* __restrict__ Xp, const void* __restrict__ w,
                u16* __restrict__ Yp, const int* __restrict__ flag) {
  const int tid = threadIdx.x;
  const int wave = tid >> 6, lane = tid & 63;
  const int o = blockIdx.x * 2 + (wave >> 3);
  const int bp = blockIdx.y * 8 + (wave & 7);      // b-pair index, b0 = 2*bp
  const int m = lane * 2;
  const int mode = flag[0];

  const uint4* X4 = (const uint4*)Xp + (size_t)bp * 64 + lane;

  float ar[2][2] = {}, ai[2][2] = {};    // [b][parity]

  if (mode == 0) {
    const float* wb = (const float*)w + 2u * ((size_t)o * 32768 + m);
#pragma unroll 8
    for (int ic = 0; ic < 256; ++ic) {
      float4 wp = *(const float4*)&wb[(size_t)ic * 256];
      uint4 xv = X4[(size_t)ic * 1024];
      float wr0 = wp.x, wi0 = wp.y, wr1 = wp.z, wi1 = wp.w;
      float xr, xi;
      xr = blo(xv.x); xi = bhi(xv.x);
      ar[0][0] = fmaf(xr, wr0, fmaf(-xi, wi0, ar[0][0]));
      ai[0][0] = fmaf(xr, wi0, fmaf(xi, wr0, ai[0][0]));
      xr = blo(xv.y); xi = bhi(xv.y);
      ar[0][1] = fmaf(xr, wr1, fmaf(-xi, wi1, ar[0][1]));
      ai[0][1] = fmaf(xr, wi1, fmaf(xi, wr1, ai[0][1]));
      xr = blo(xv.z); xi = bhi(xv.z);
      ar[1][0] = fmaf(xr, wr0, fmaf(-xi, wi0, ar[1][0]));
      ai[1][0] = fmaf(xr, wi0, fmaf(xi, wr0, ai[1][0]));
      xr = blo(xv.w); xi = bhi(xv.w);
      ar[1][1] = fmaf(xr, wr1, fmaf(-xi, wi1, ar[1][1]));
      ai[1][1] = fmaf(xr, wi1, fmaf(xi, wr1, ai[1][1]));
    }
  } else {
    const u32* wb = (const u32*)w + (size_t)o * 32768 + m;
#pragma unroll 8
    for (int ic = 0; ic < 256; ++ic) {
      uint2 wp = *(const uint2*)&wb[(size_t)ic * 128];
      uint4 xv = X4[(size_t)ic * 1024];
      float wr0 = blo(wp.x), wi0 = bhi(wp.x), wr1 = blo(wp.y), wi1 = bhi(wp.y);
      float xr, xi;
      xr = blo(xv.x); xi = bhi(xv.x);
      ar[0][0] = fmaf(xr, wr0, fmaf(-xi, wi0, ar[0][0]));
      ai[0][0] = fmaf(xr, wi0, fmaf(xi, wr0, ai[0][0]));
      xr = blo(xv.y); xi = bhi(xv.y);
      ar[0][1] = fmaf(xr, wr1, fmaf(-xi, wi1, ar[0][1]));
      ai[0][1] = fmaf(xr, wi1, fmaf(xi, wr1, ai[0][1]));
      xr = blo(xv.z); xi = bhi(xv.z);
      ar[1][0] = fmaf(xr, wr0, fmaf(-xi, wi0, ar[1][0]));
      ai[1][0] = fmaf(xr, wi0, fmaf(xi, wr0, ai[1][0]));
      xr = blo(xv.w); xi = bhi(xv.w);
      ar[1][1] = fmaf(xr, wr1, fmaf(-xi, wi1, ar[1][1]));
      ai[1][1] = fmaf(xr, wi1, fmaf(xi, wr1, ai[1][1]));
    }
  }

  const float sIm = 2.0f / 4096.0f;
  const float sRe0 = (m == 0) ? (1.0f / 4096.0f) : (2.0f / 4096.0f);
  const float sRe1 = 2.0f / 4096.0f;
  u32* Yp32 = (u32*)Yp;
#pragma unroll
  for (int jb = 0; jb < 2; ++jb) {
    int b = bp * 2 + jb;
    size_t base = ((size_t)(b * 256 + o)) * 128;   // u32 index
    u32 we = (u32)f2b(ar[jb][0] * sRe0) | ((u32)f2b(ai[jb][0] * sIm) << 16);
    u32 wo = (u32)f2b(ar[jb][1] * sRe1) | ((u32)f2b(ai[jb][1] * sIm) << 16);
    Yp32[base + lane] = we;          // even-mode (re,im) pair, word lane
    Yp32[base + 64 + lane] = wo;     // odd-mode  (re,im) pair, word 64+lane
  }
}

// ---------------------------------------------------------------- launch
extern "C" void kernel_launch(void* const* d_in, const int* in_sizes, int n_in,
                              void* d_out, int out_size, void* d_ws, size_t ws_size,
                              hipStream_t stream) {
  const void* x = d_in[0];                // (32,256,4096) fp32 or bf16
  const void* w = d_in[1];                // (256,256,128,2) fp32 or bf16

  char* ws = (char*)d_ws;
  int*  flag  = (int*)(ws);
  u16*  Bas1P = (u16*)(ws + (1u << 20)); // 1 MB  [r=256][t'=2048] fwd parity
  u16*  Bas2P = (u16*)(ws + (2u << 20)); // 1 MB  [t'=2048][c=256] inv parity
  u32*  Xp4   = (u32*)(ws + (4u << 20)); // 4 MB  [ic][bp][j] uint4(e0,o0,e1,o1)
  u16*  Yp    = (u16*)(ws + (8u << 20)); // 4 MB  parity-grouped (re,im)

  probe_kernel<<<dim3(1), dim3(256), 0, stream>>>((const u16*)x, flag);
  basis_kernel<<<dim3(2048), dim3(256), 0, stream>>>(Bas1P, Bas2P);

  // radix-2 folded forward rDFT: z=parity, K=2048, fused pack into Xp4
  gemm_nt<32, 128, 2, true><<<dim3(1, 256, 2), dim3(256), 0, stream>>>(
      x, Bas1P, 2048, MLEN, 2048, Xp4, 0, nullptr, nullptr, flag);

  // per-mode complex channel mix -> Yp (bf16, irfft scaling folded in)
  mix_kernel<<<dim3(128, 2), dim3(1024), 0, stream>>>(Xp4, w, Yp, flag);

  // radix-2 folded inverse DFT + LeakyReLU + residual (butterfly epilogue)
  gemm_nt<128, 64, 1, false><<<dim3(32, 64, 1), dim3(256), 0, stream>>>(
      Yp, Bas2P, 256, 256, 256, nullptr, MLEN, x, d_out, flag);
}